// Round 11
// baseline (295.736 us; speedup 1.0000x reference)
//
#include <hip/hip_runtime.h>
#include <math.h>

// ---------------------------------------------------------------------------
// GAT 3-layer pipeline. bf16 features + MFMA GEMMs, fused CSR edge-softmax.
//   el = h @ wl.T, wl[h,:] = al[h,:] @ Wsrc_h   (no fs materialization)
//   agg = (softmax-weighted sum of raw feats) @ Wsrc_h.T  (aggregate first)
// ALL dot kernels are MFMA-based ([N x K] @ [K x 8] GEMM-dot; no shuffles).
// CSR: concat counts, parallel 2-launch scan, cursor-atomic scatter.
// GEMM: global_load_lds(16B) staging, XOR seg-swizzle both sides.
// ---------------------------------------------------------------------------

#define E0 375000
#define E1 90000
#define E2 10240
#define ETOT (E0 + E1 + E2)
#define ND0 25000
#define ND1 6000
#define ND2 1024
#define NTOT (ND0 + ND1 + ND2)   /* 32024 */
#define NCH ((NTOT + 127) / 128) /* 251 */

static const int L_NS[3]   = {150000, 25000, 6000};
static const int L_ND[3]   = {ND0, ND1, ND2};
static const int L_FIN[3]  = {256, 512, 512};
static const int L_FOUT[3] = {128, 128, 47};

typedef short bf8_t __attribute__((ext_vector_type(8)));
typedef float f32x4 __attribute__((ext_vector_type(4)));

__device__ __forceinline__ float lrelu(float v) { return v >= 0.f ? v : 0.2f * v; }
__device__ __forceinline__ unsigned short f2b(float f) {
  unsigned u = __float_as_uint(f);
  unsigned r = u + 0x7fffu + ((u >> 16) & 1u);
  return (unsigned short)(r >> 16);
}
__device__ __forceinline__ float b2f(unsigned v) {  // low 16 bits
  return __uint_as_float(v << 16);
}

__device__ __forceinline__ void gload16(const unsigned short* g, unsigned short* l) {
  __builtin_amdgcn_global_load_lds(
      (const __attribute__((address_space(1))) unsigned int*)g,
      (__attribute__((address_space(3))) unsigned int*)l, 16, 0, 0);
}

// ---------------- prologue (one-shot, topology/weights only) ----------------

// fused: edge counting (fire-and-forget atomics) + wlr tables + bf16 weights
__global__ void k_prep_count(
    const int* __restrict__ d0, const int* __restrict__ d1,
    const int* __restrict__ d2, int* __restrict__ cntAll,
    const float* __restrict__ Ws0, const float* __restrict__ Wd0,
    const float* __restrict__ al0, const float* __restrict__ ar0,
    const float* __restrict__ Ws1, const float* __restrict__ Wd1,
    const float* __restrict__ al1, const float* __restrict__ ar1,
    const float* __restrict__ Ws2, const float* __restrict__ Wd2,
    const float* __restrict__ al2, const float* __restrict__ ar2,
    unsigned short* __restrict__ wlrb, unsigned short* __restrict__ wblr1,
    unsigned short* __restrict__ wblr2,
    unsigned short* __restrict__ B0, unsigned short* __restrict__ B1,
    unsigned short* __restrict__ B2) {
  int gid = blockIdx.x * 256 + threadIdx.x;
  // edge counts into concatenated counter array (no return use)
  if (gid < ETOT) {
    int goff, dv;
    if (gid < E0) { goff = 0; dv = d0[gid]; }
    else if (gid < E0 + E1) { goff = ND0; dv = d1[gid - E0]; }
    else { goff = ND0 + ND1; dv = d2[gid - E0 - E1]; }
    atomicAdd(&cntAll[goff + dv], 1);
  }
  // L0 MFMA-dot B table: bf16 [16][264], rows 8-15 zero
  if (gid < 2048) {
    int h = gid >> 8, k = gid & 255;  // h 0-3: wl, 4-7: wr
    const float* W = (h < 4) ? Ws0 : Wd0;
    const float* a = (h < 4) ? al0 : ar0;
    int hh = h & 3;
    float acc = 0.f;
    for (int d = 0; d < 128; ++d)
      acc += a[hh * 128 + d] * W[(size_t)(hh * 128 + d) * 256 + k];
    wlrb[h * 264 + k] = f2b(acc);
  } else if (gid < 4096) {
    int idx = gid - 2048;
    wlrb[(8 + (idx >> 8)) * 264 + (idx & 255)] = 0;  // zero pad rows
  } else if (gid < 12288) {
    // L1/L2 GEMM-dot B tables: bf16 [8][512] (row r: r<4 wl_h, r>=4 wr_h)
    int idx = gid - 4096;  // 0..8191
    unsigned short* wb; const float *Ws, *Wd, *al, *ar; int Fout;
    if (idx < 4096) { wb = wblr1; Ws = Ws1; Wd = Wd1; al = al1; ar = ar1; Fout = 128; }
    else { idx -= 4096; wb = wblr2; Ws = Ws2; Wd = Wd2; al = al2; ar = ar2; Fout = 47; }
    int r = idx >> 9, k = idx & 511;
    const float* W = (r < 4) ? Ws : Wd;
    const float* a = (r < 4) ? al : ar;
    int hh = r & 3;
    float acc = 0.f;
    for (int d = 0; d < Fout; ++d)
      acc += a[hh * Fout + d] * W[(size_t)(hh * Fout + d) * 512 + k];
    wb[r * 512 + k] = f2b(acc);
  }
  // bf16 weight conversion
  const int n0 = 512 * 256, n1 = 512 * 512, n2 = 188 * 512;
  for (int i = gid; i < n0 + n1 + n2; i += gridDim.x * 256) {
    if (i < n0) B0[i] = f2b(Ws0[i]);
    else if (i < n0 + n1) B1[i - n0] = f2b(Ws1[i - n0]);
    else B2[i - n0 - n1] = f2b(Ws2[i - n0 - n1]);
  }
}

// parallel chunked scan, phase A: per-128-chunk local exclusive scan + totals
__global__ __launch_bounds__(128) void k_scanA(const int* __restrict__ cnt,
                                               int* __restrict__ S,
                                               int* __restrict__ btot, int n) {
  __shared__ int wt[2];
  int c = blockIdx.x, t = threadIdx.x, lane = t & 63, w = t >> 6;
  int g = c * 128 + t;
  int v = (g < n) ? cnt[g] : 0;
  int incl = v;
  for (int off = 1; off < 64; off <<= 1) {
    int u = __shfl_up(incl, off);
    if (lane >= off) incl += u;
  }
  if (lane == 63) wt[w] = incl;
  __syncthreads();
  int base = (w == 1) ? wt[0] : 0;
  if (g < n) S[g] = incl - v + base;
  if (t == 127) btot[c] = wt[0] + wt[1];
}

// phase B: add chunk bases; emit cursor copy for scatter
__global__ __launch_bounds__(256) void k_scanB(const int* __restrict__ btot,
                                               int* __restrict__ S,
                                               int* __restrict__ cursor,
                                               int n, int etot) {
  __shared__ int tv[256];
  int c = blockIdx.x, t = threadIdx.x;
  int own = (t < NCH) ? btot[t] : 0;
  tv[t] = own;
  __syncthreads();
  for (int off = 1; off < 256; off <<= 1) {
    int u = (t >= off) ? tv[t - off] : 0;
    __syncthreads();
    tv[t] += u;
    __syncthreads();
  }
  int base = tv[c] - btot[c];  // exclusive base of chunk c
  int g = c * 128 + (t & 127);
  if (t < 128 && g < n) {
    int s = S[g] + base;
    S[g] = s;
    cursor[g] = s;
  }
  if (c == 0 && t == 255) S[n] = etot;
}

__global__ void k_scatter_all(
    const int* __restrict__ s0, const int* __restrict__ d0,
    const int* __restrict__ s1, const int* __restrict__ d1,
    const int* __restrict__ s2, const int* __restrict__ d2,
    int* __restrict__ cursor, int* __restrict__ cvAll) {
  int g = blockIdx.x * 256 + threadIdx.x;
  if (g >= ETOT) return;
  int goff, dv, sv;
  if (g < E0) { goff = 0; dv = d0[g]; sv = s0[g]; }
  else if (g < E0 + E1) { int e = g - E0; goff = ND0; dv = d1[e]; sv = s1[e]; }
  else { int e = g - E0 - E1; goff = ND0 + ND1; dv = d2[e]; sv = s2[e]; }
  int slot = atomicAdd(&cursor[goff + dv], 1);
  cvAll[slot] = sv;
}

// ---------------- per-layer feature kernels ----------------

// L0: MFMA dot. Block = 128 nodes, 256 threads (4 waves). fp32 x, cvt in LDS.
__global__ __launch_bounds__(256) void k_dotc_mfma(
    const float* __restrict__ x, const unsigned short* __restrict__ wlrb,
    float* __restrict__ ell, float* __restrict__ err, int Ns, int Nd) {
  __shared__ unsigned short As[128 * 72];
  __shared__ unsigned short Bs[16 * 264];
  const int tid = threadIdx.x;
  const int w = tid >> 6, lane = tid & 63;
  const int bm = blockIdx.x * 128;
  const int rowg = tid >> 4;   // 0..15
  const int seg  = tid & 15;   // 0..15
  for (int i = tid; i < 16 * 264; i += 256) Bs[i] = wlrb[i];
  f32x4 acc[2] = {};
  for (int k0 = 0; k0 < 256; k0 += 64) {
    __syncthreads();
#pragma unroll
    for (int i = 0; i < 8; ++i) {
      int row = rowg + i * 16;
      int gm = bm + row;
      int gmc = gm < Ns ? gm : Ns - 1;
      float4 a = *reinterpret_cast<const float4*>(x + (size_t)gmc * 256 + k0 + seg * 4);
      ushort4 ub;
      ub.x = f2b(a.x); ub.y = f2b(a.y); ub.z = f2b(a.z); ub.w = f2b(a.w);
      *reinterpret_cast<ushort4*>(&As[row * 72 + seg * 4]) = ub;
    }
    __syncthreads();
    const int ra = w * 32 + (lane & 15);
    const int kf = (lane >> 4) * 8;
#pragma unroll
    for (int ks = 0; ks < 2; ++ks) {
      bf8_t b0 = *reinterpret_cast<const bf8_t*>(&Bs[(lane & 15) * 264 + k0 + ks * 32 + kf]);
      bf8_t a0 = *reinterpret_cast<const bf8_t*>(&As[ra * 72 + ks * 32 + kf]);
      bf8_t a1 = *reinterpret_cast<const bf8_t*>(&As[(ra + 16) * 72 + ks * 32 + kf]);
      acc[0] = __builtin_amdgcn_mfma_f32_16x16x32_bf16(a0, b0, acc[0], 0, 0, 0);
      acc[1] = __builtin_amdgcn_mfma_f32_16x16x32_bf16(a1, b0, acc[1], 0, 0, 0);
    }
  }
  int col = lane & 15;
#pragma unroll
  for (int fm = 0; fm < 2; ++fm) {
#pragma unroll
    for (int j = 0; j < 4; ++j) {
      int node = bm + w * 32 + fm * 16 + (lane >> 4) * 4 + j;
      if (node >= Ns) continue;
      float v = acc[fm][j];
      if (col < 4) ell[(size_t)node * 4 + col] = v;
      else if (col < 8 && node < Nd) err[(size_t)node * 4 + (col - 4)] = v;
    }
  }
}

// L1/L2: GEMM-dot [M x 512] @ [512 x 8] -> ell/err. bf16 input rows, lda=512.
// Same staging structure as k_gemm_mfma (BN=32, N=8 clamp).
__global__ __launch_bounds__(256) void k_dot_gemm(
    const unsigned short* __restrict__ Hs, const unsigned short* __restrict__ Wb8,
    float* __restrict__ ell, float* __restrict__ err, int M, int Nd) {
  constexpr int K = 512;
  __shared__ unsigned short As[128 * 64];
  __shared__ unsigned short Bs[32 * 64];
  const int tid = threadIdx.x;
  const int w = tid >> 6, lane = tid & 63;
  const int bm = blockIdx.x * 128;
  const int lrow = lane >> 3;
  const int gseg = (lane & 7) ^ lrow;
  f32x4 acc[2][2];
#pragma unroll
  for (int i = 0; i < 2; ++i)
#pragma unroll
    for (int j = 0; j < 2; ++j) acc[i][j] = (f32x4){0.f, 0.f, 0.f, 0.f};

  for (int k0 = 0; k0 < K; k0 += 64) {
    __syncthreads();
#pragma unroll
    for (int i = 0; i < 4; ++i) {
      int ch = w * 4 + i;
      int row = ch * 8 + lrow;
      int gm = bm + row; gm = gm < M ? gm : M - 1;
      gload16(Hs + (size_t)gm * K + k0 + gseg * 8, As + ch * 512);
    }
    {
      int ch = w;                 // BI=1: 4 waves cover rows 0..31
      int row = ch * 8 + lrow;
      int gn = row < 8 ? row : 7; // clamp to N=8 rows of Wb8
      gload16(Wb8 + (size_t)gn * K + k0 + gseg * 8, Bs + ch * 512);
    }
    __syncthreads();
    const int ra = w * 32 + (lane & 15);
#pragma unroll
    for (int ks = 0; ks < 2; ++ks) {
      int cs = ((((ks << 2) + (lane >> 4)) ^ (lane & 7)) << 3);
      bf8_t a0 = *reinterpret_cast<const bf8_t*>(As + ra * 64 + cs);
      bf8_t a1 = *reinterpret_cast<const bf8_t*>(As + (ra + 16) * 64 + cs);
#pragma unroll
      for (int fn = 0; fn < 2; ++fn) {
        bf8_t bf = *reinterpret_cast<const bf8_t*>(Bs + (fn * 16 + (lane & 15)) * 64 + cs);
        acc[0][fn] = __builtin_amdgcn_mfma_f32_16x16x32_bf16(a0, bf, acc[0][fn], 0, 0, 0);
        acc[1][fn] = __builtin_amdgcn_mfma_f32_16x16x32_bf16(a1, bf, acc[1][fn], 0, 0, 0);
      }
    }
  }
  int col = lane & 15;  // fn=0 fragment holds cols 0..15; only 0..7 matter
#pragma unroll
  for (int fm = 0; fm < 2; ++fm) {
#pragma unroll
    for (int j = 0; j < 4; ++j) {
      int node = bm + w * 32 + fm * 16 + (lane >> 4) * 4 + j;
      if (node >= M) continue;
      float v = acc[fm][0][j];
      if (col < 4) ell[(size_t)node * 4 + col] = v;
      else if (col < 8 && node < Nd) err[(size_t)node * 4 + (col - 4)] = v;
    }
  }
}

#define GAT_ACCF(w4, xr)                                                       \
  {                                                                            \
    float w0 = w4.x, w1 = w4.y, w2 = w4.z, w3 = w4.w;                          \
    s0 += w0; s1 += w1; s2 += w2; s3 += w3;                                    \
    float x0 = xr.x, x1 = xr.y, x2 = xr.z, x3 = xr.w;                          \
    acc[0][0] = fmaf(w0, x0, acc[0][0]); acc[0][1] = fmaf(w0, x1, acc[0][1]);  \
    acc[0][2] = fmaf(w0, x2, acc[0][2]); acc[0][3] = fmaf(w0, x3, acc[0][3]);  \
    acc[1][0] = fmaf(w1, x0, acc[1][0]); acc[1][1] = fmaf(w1, x1, acc[1][1]);  \
    acc[1][2] = fmaf(w1, x2, acc[1][2]); acc[1][3] = fmaf(w1, x3, acc[1][3]);  \
    acc[2][0] = fmaf(w2, x0, acc[2][0]); acc[2][1] = fmaf(w2, x1, acc[2][1]);  \
    acc[2][2] = fmaf(w2, x2, acc[2][2]); acc[2][3] = fmaf(w2, x3, acc[2][3]);  \
    acc[3][0] = fmaf(w3, x0, acc[3][0]); acc[3][1] = fmaf(w3, x1, acc[3][1]);  \
    acc[3][2] = fmaf(w3, x2, acc[3][2]); acc[3][3] = fmaf(w3, x3, acc[3][3]);  \
  }

// L0 gather: reads fp32 x directly (L3-resident). 4 waves/block, barrier-free.
__global__ __launch_bounds__(256) void k_gather4_f32(
    const float* __restrict__ X, const float* __restrict__ ell,
    const float* __restrict__ err, const int* __restrict__ rowptr,
    const int* __restrict__ colv, unsigned short* __restrict__ Z, int Nd) {
  constexpr int CAP = 256;
  __shared__ float4 esm_all[4][CAP];
  __shared__ int csm_all[4][CAP];
  int w = threadIdx.x >> 6, lane = threadIdx.x & 63;
  int n = blockIdx.x * 4 + w;
  if (n >= Nd) return;
  float4* esm = esm_all[w];
  int* csm = csm_all[w];
  int beg = rowptr[n], cnt = rowptr[n + 1] - beg;
  float4 er4 = *reinterpret_cast<const float4*>(err + (size_t)n * 4);
  float m0 = -INFINITY, m1 = -INFINITY, m2 = -INFINITY, m3 = -INFINITY;
  for (int i = lane; i < cnt; i += 64) {
    int c = colv[beg + i];
    float4 el4 = *reinterpret_cast<const float4*>(ell + (size_t)c * 4);
    float4 e4;
    e4.x = lrelu(el4.x + er4.x); e4.y = lrelu(el4.y + er4.y);
    e4.z = lrelu(el4.z + er4.z); e4.w = lrelu(el4.w + er4.w);
    if (i < CAP) { csm[i] = c; esm[i] = e4; }
    m0 = fmaxf(m0, e4.x); m1 = fmaxf(m1, e4.y);
    m2 = fmaxf(m2, e4.z); m3 = fmaxf(m3, e4.w);
  }
  for (int off = 32; off > 0; off >>= 1) {
    m0 = fmaxf(m0, __shfl_xor(m0, off));
    m1 = fmaxf(m1, __shfl_xor(m1, off));
    m2 = fmaxf(m2, __shfl_xor(m2, off));
    m3 = fmaxf(m3, __shfl_xor(m3, off));
  }
  __builtin_amdgcn_sched_barrier(0);  // wave-private LDS: order writes before reads
  float s0 = 0.f, s1 = 0.f, s2 = 0.f, s3 = 0.f;
  float acc[4][4] = {};
  if (cnt <= CAP) {
    for (int i = lane; i < cnt; i += 64) {
      float4 e = esm[i];
      esm[i] = make_float4(__expf(e.x - m0), __expf(e.y - m1),
                           __expf(e.z - m2), __expf(e.w - m3));
    }
    __builtin_amdgcn_sched_barrier(0);
    int j = 0;
    for (; j + 4 <= cnt; j += 4) {
      int c0 = csm[j], c1 = csm[j + 1], c2 = csm[j + 2], c3 = csm[j + 3];
      float4 wa = esm[j], wb = esm[j + 1], wc = esm[j + 2], wd = esm[j + 3];
      float4 xa = *reinterpret_cast<const float4*>(X + (size_t)c0 * 256 + lane * 4);
      float4 xb = *reinterpret_cast<const float4*>(X + (size_t)c1 * 256 + lane * 4);
      float4 xc = *reinterpret_cast<const float4*>(X + (size_t)c2 * 256 + lane * 4);
      float4 xd = *reinterpret_cast<const float4*>(X + (size_t)c3 * 256 + lane * 4);
      GAT_ACCF(wa, xa); GAT_ACCF(wb, xb); GAT_ACCF(wc, xc); GAT_ACCF(wd, xd);
    }
    for (; j < cnt; ++j) {
      float4 wa = esm[j];
      float4 xa = *reinterpret_cast<const float4*>(X + (size_t)csm[j] * 256 + lane * 4);
      GAT_ACCF(wa, xa);
    }
  } else {
    for (int j = 0; j < cnt; ++j) {
      int c = colv[beg + j];
      float4 el4 = *reinterpret_cast<const float4*>(ell + (size_t)c * 4);
      float4 w4;
      w4.x = __expf(lrelu(el4.x + er4.x) - m0);
      w4.y = __expf(lrelu(el4.y + er4.y) - m1);
      w4.z = __expf(lrelu(el4.z + er4.z) - m2);
      w4.w = __expf(lrelu(el4.w + er4.w) - m3);
      float4 xa = *reinterpret_cast<const float4*>(X + (size_t)c * 256 + lane * 4);
      GAT_ACCF(w4, xa);
    }
  }
  float inv[4];
  inv[0] = 1.f / fmaxf(s0, 1e-9f); inv[1] = 1.f / fmaxf(s1, 1e-9f);
  inv[2] = 1.f / fmaxf(s2, 1e-9f); inv[3] = 1.f / fmaxf(s3, 1e-9f);
#pragma unroll
  for (int h = 0; h < 4; ++h) {
    ushort4 o;
    o.x = f2b(acc[h][0] * inv[h]); o.y = f2b(acc[h][1] * inv[h]);
    o.z = f2b(acc[h][2] * inv[h]); o.w = f2b(acc[h][3] * inv[h]);
    *reinterpret_cast<ushort4*>(Z + (size_t)n * 1024 + h * 256 + lane * 4) = o;
  }
}

#define GAT_ACC(w4, xr)                                                        \
  {                                                                            \
    float w0 = w4.x, w1 = w4.y, w2 = w4.z, w3 = w4.w;                          \
    s0 += w0; s1 += w1; s2 += w2; s3 += w3;                                    \
    float x0 = b2f(xr.x), x1 = b2f(xr.y), x2 = b2f(xr.z), x3 = b2f(xr.w);      \
    acc[0][0] = fmaf(w0, x0, acc[0][0]); acc[0][1] = fmaf(w0, x1, acc[0][1]);  \
    acc[0][2] = fmaf(w0, x2, acc[0][2]); acc[0][3] = fmaf(w0, x3, acc[0][3]);  \
    acc[1][0] = fmaf(w1, x0, acc[1][0]); acc[1][1] = fmaf(w1, x1, acc[1][1]);  \
    acc[1][2] = fmaf(w1, x2, acc[1][2]); acc[1][3] = fmaf(w1, x3, acc[1][3]);  \
    acc[2][0] = fmaf(w2, x0, acc[2][0]); acc[2][1] = fmaf(w2, x1, acc[2][1]);  \
    acc[2][2] = fmaf(w2, x2, acc[2][2]); acc[2][3] = fmaf(w2, x3, acc[2][3]);  \
    acc[3][0] = fmaf(w3, x0, acc[3][0]); acc[3][1] = fmaf(w3, x1, acc[3][1]);  \
    acc[3][2] = fmaf(w3, x2, acc[3][2]); acc[3][3] = fmaf(w3, x3, acc[3][3]);  \
  }

// FIN=512 gather (L1/L2): block = one dst node, 128 threads (2 waves).
__global__ __launch_bounds__(128) void k_gather_512(
    const unsigned short* __restrict__ Hs, const float* __restrict__ ell,
    const float* __restrict__ err, const int* __restrict__ rowptr,
    const int* __restrict__ colv, unsigned short* __restrict__ Z) {
  constexpr int TB = 128;
  constexpr int CAP = 256;
  int n = blockIdx.x, t = threadIdx.x;
  int beg = rowptr[n], cnt = rowptr[n + 1] - beg;
  float4 er4 = *reinterpret_cast<const float4*>(err + (size_t)n * 4);
  __shared__ float4 esm[CAP];
  __shared__ int csm[CAP];
  __shared__ float4 wred[2];
  float m0 = -INFINITY, m1 = -INFINITY, m2 = -INFINITY, m3 = -INFINITY;
  for (int i = t; i < cnt; i += TB) {
    int c = colv[beg + i];
    float4 el4 = *reinterpret_cast<const float4*>(ell + (size_t)c * 4);
    float4 e4;
    e4.x = lrelu(el4.x + er4.x); e4.y = lrelu(el4.y + er4.y);
    e4.z = lrelu(el4.z + er4.z); e4.w = lrelu(el4.w + er4.w);
    if (i < CAP) { csm[i] = c; esm[i] = e4; }
    m0 = fmaxf(m0, e4.x); m1 = fmaxf(m1, e4.y);
    m2 = fmaxf(m2, e4.z); m3 = fmaxf(m3, e4.w);
  }
  for (int off = 32; off > 0; off >>= 1) {
    m0 = fmaxf(m0, __shfl_xor(m0, off));
    m1 = fmaxf(m1, __shfl_xor(m1, off));
    m2 = fmaxf(m2, __shfl_xor(m2, off));
    m3 = fmaxf(m3, __shfl_xor(m3, off));
  }
  if ((t & 63) == 0) wred[t >> 6] = make_float4(m0, m1, m2, m3);
  __syncthreads();
  {
    float4 wa = wred[0], wb = wred[1];
    m0 = fmaxf(wa.x, wb.x); m1 = fmaxf(wa.y, wb.y);
    m2 = fmaxf(wa.z, wb.z); m3 = fmaxf(wa.w, wb.w);
  }
  float s0 = 0.f, s1 = 0.f, s2 = 0.f, s3 = 0.f;
  float acc[4][4] = {};
  if (cnt <= CAP) {
    for (int i = t; i < cnt; i += TB) {
      float4 e = esm[i];
      esm[i] = make_float4(__expf(e.x - m0), __expf(e.y - m1),
                           __expf(e.z - m2), __expf(e.w - m3));
    }
    __syncthreads();
    int j = 0;
    for (; j + 2 <= cnt; j += 2) {
      float4 wa = esm[j], wb = esm[j + 1];
      int ca = csm[j], cb = csm[j + 1];
      ushort4 xa = *reinterpret_cast<const ushort4*>(Hs + (size_t)ca * 512 + t * 4);
      ushort4 xb = *reinterpret_cast<const ushort4*>(Hs + (size_t)cb * 512 + t * 4);
      GAT_ACC(wa, xa);
      GAT_ACC(wb, xb);
    }
    if (j < cnt) {
      float4 wa = esm[j];
      ushort4 xa = *reinterpret_cast<const ushort4*>(Hs + (size_t)csm[j] * 512 + t * 4);
      GAT_ACC(wa, xa);
    }
  } else {
    for (int j = 0; j < cnt; ++j) {
      int c = colv[beg + j];
      float4 el4 = *reinterpret_cast<const float4*>(ell + (size_t)c * 4);
      float4 w4;
      w4.x = __expf(lrelu(el4.x + er4.x) - m0);
      w4.y = __expf(lrelu(el4.y + er4.y) - m1);
      w4.z = __expf(lrelu(el4.z + er4.z) - m2);
      w4.w = __expf(lrelu(el4.w + er4.w) - m3);
      ushort4 xa = *reinterpret_cast<const ushort4*>(Hs + (size_t)c * 512 + t * 4);
      GAT_ACC(w4, xa);
    }
  }
  float inv[4];
  inv[0] = 1.f / fmaxf(s0, 1e-9f); inv[1] = 1.f / fmaxf(s1, 1e-9f);
  inv[2] = 1.f / fmaxf(s2, 1e-9f); inv[3] = 1.f / fmaxf(s3, 1e-9f);
#pragma unroll
  for (int h = 0; h < 4; ++h) {
    ushort4 o;
    o.x = f2b(acc[h][0] * inv[h]); o.y = f2b(acc[h][1] * inv[h]);
    o.z = f2b(acc[h][2] * inv[h]); o.w = f2b(acc[h][3] * inv[h]);
    *reinterpret_cast<ushort4*>(Z + (size_t)n * 2048 + h * 512 + t * 4) = o;
  }
}
#undef GAT_ACC
#undef GAT_ACCF

// bf16 MFMA GEMM (unchanged, proven)
template <int BN, bool ACT, bool OUTBF>
__global__ __launch_bounds__(256) void k_gemm_mfma(
    const unsigned short* __restrict__ Zb, const unsigned short* __restrict__ Wb,
    const float* __restrict__ bias, void* __restrict__ outv,
    int M, int N, int K) {
  constexpr int FN = BN / 16;
  constexpr int AI = 4;
  constexpr int BI = BN / 32;
  int h = blockIdx.z;
  __shared__ unsigned short As[128 * 64];
  __shared__ unsigned short Bs[BN * 64];
  const int tid = threadIdx.x;
  const int w = tid >> 6, lane = tid & 63;
  const int bm = blockIdx.x * 128, bn = blockIdx.y * BN;
  const int lda = 4 * K;
  const unsigned short* Ag = Zb + (size_t)h * K;
  const unsigned short* Bg = Wb + (size_t)h * N * K;
  const int lrow = lane >> 3;
  const int gseg = (lane & 7) ^ lrow;
  f32x4 acc[2][FN];
#pragma unroll
  for (int i = 0; i < 2; ++i)
#pragma unroll
    for (int j = 0; j < FN; ++j) acc[i][j] = (f32x4){0.f, 0.f, 0.f, 0.f};

  for (int k0 = 0; k0 < K; k0 += 64) {
    __syncthreads();
#pragma unroll
    for (int i = 0; i < AI; ++i) {
      int ch = w * AI + i;
      int row = ch * 8 + lrow;
      int gm = bm + row; gm = gm < M ? gm : M - 1;
      gload16(Ag + (size_t)gm * lda + k0 + gseg * 8, As + ch * 512);
    }
#pragma unroll
    for (int i = 0; i < BI; ++i) {
      int ch = w * BI + i;
      int row = ch * 8 + lrow;
      int gn = bn + row; gn = gn < N ? gn : N - 1;
      gload16(Bg + (size_t)gn * K + k0 + gseg * 8, Bs + ch * 512);
    }
    __syncthreads();
    const int ra = w * 32 + (lane & 15);
#pragma unroll
    for (int ks = 0; ks < 2; ++ks) {
      int cs = ((((ks << 2) + (lane >> 4)) ^ (lane & 7)) << 3);
      bf8_t a0 = *reinterpret_cast<const bf8_t*>(As + ra * 64 + cs);
      bf8_t a1 = *reinterpret_cast<const bf8_t*>(As + (ra + 16) * 64 + cs);
#pragma unroll
      for (int fn = 0; fn < FN; ++fn) {
        bf8_t bf = *reinterpret_cast<const bf8_t*>(Bs + (fn * 16 + (lane & 15)) * 64 + cs);
        acc[0][fn] = __builtin_amdgcn_mfma_f32_16x16x32_bf16(a0, bf, acc[0][fn], 0, 0, 0);
        acc[1][fn] = __builtin_amdgcn_mfma_f32_16x16x32_bf16(a1, bf, acc[1][fn], 0, 0, 0);
      }
    }
  }
  int ldo = 4 * N;
#pragma unroll
  for (int fm = 0; fm < 2; ++fm) {
#pragma unroll
    for (int fn = 0; fn < FN; ++fn) {
      int colb = bn + fn * 16 + (lane & 15);
      if (colb >= N) continue;
      float bv = bias[h * N + colb];
#pragma unroll
      for (int j = 0; j < 4; ++j) {
        int rowb = bm + w * 32 + fm * 16 + (lane >> 4) * 4 + j;
        if (rowb >= M) continue;
        float v = acc[fm][fn][j] + bv;
        if (ACT) v = v > 0.f ? v : (__expf(v) - 1.f);
        size_t off = (size_t)rowb * ldo + (size_t)h * N + colb;
        if (OUTBF) ((unsigned short*)outv)[off] = f2b(v);
        else ((float*)outv)[off] = v;
      }
    }
  }
}

// mean over 4 heads (C=47) + log_softmax; one wave per node
__global__ __launch_bounds__(256) void k_mean_lsm(const float* __restrict__ rst2,
                                                  float* __restrict__ out, int Nd) {
  int node = blockIdx.x * 4 + (threadIdx.x >> 6);
  int lane = threadIdx.x & 63;
  if (node >= Nd) return;
  const float* r = rst2 + (size_t)node * 188;
  float vv = 0.f;
  if (lane < 47)
    vv = 0.25f * (r[lane] + r[47 + lane] + r[94 + lane] + r[141 + lane]);
  float m = (lane < 47) ? vv : -INFINITY;
  for (int off = 32; off > 0; off >>= 1) m = fmaxf(m, __shfl_xor(m, off));
  float ex = (lane < 47) ? __expf(vv - m) : 0.f;
  float ss = ex;
  for (int off = 32; off > 0; off >>= 1) ss += __shfl_xor(ss, off);
  if (lane < 47) out[(size_t)node * 47 + lane] = vv - m - logf(ss);
}

extern "C" void kernel_launch(void* const* d_in, const int* in_sizes, int n_in,
                              void* d_out, int out_size, void* d_ws, size_t ws_size,
                              hipStream_t stream) {
  (void)in_sizes; (void)n_in; (void)out_size; (void)ws_size;
  const float* x = (const float*)d_in[0];
  const int* srcs[3] = {(const int*)d_in[1], (const int*)d_in[3], (const int*)d_in[5]};
  const int* dsts[3] = {(const int*)d_in[2], (const int*)d_in[4], (const int*)d_in[6]};
  const float* Wsrc[3] = {(const float*)d_in[7], (const float*)d_in[12], (const float*)d_in[17]};
  const float* Wdst[3] = {(const float*)d_in[8], (const float*)d_in[13], (const float*)d_in[18]};
  const float* al[3]   = {(const float*)d_in[9], (const float*)d_in[14], (const float*)d_in[19]};
  const float* ar[3]   = {(const float*)d_in[10], (const float*)d_in[15], (const float*)d_in[20]};
  const float* bb[3]   = {(const float*)d_in[11], (const float*)d_in[16], (const float*)d_in[21]};

  char* p = (char*)d_ws;
  auto alloc = [&](size_t bytes) -> void* {
    void* r = (void*)p;
    p += (bytes + 255) & ~(size_t)255;
    return r;
  };
  unsigned short* zbf = (unsigned short*)alloc((size_t)25000 * 1024 * 2);
  unsigned short* h1  = (unsigned short*)alloc((size_t)25000 * 512 * 2);
  unsigned short* h2  = (unsigned short*)alloc((size_t)6000 * 512 * 2);
  float* rst2   = (float*)alloc((size_t)1024 * 188 * 4);
  unsigned short* Wb0 = (unsigned short*)alloc((size_t)512 * 256 * 2);
  unsigned short* Wb1 = (unsigned short*)alloc((size_t)512 * 512 * 2);
  unsigned short* Wb2 = (unsigned short*)alloc((size_t)188 * 512 * 2);
  float* ell    = (float*)alloc((size_t)150000 * 4 * 4);
  float* err    = (float*)alloc((size_t)25000 * 4 * 4);
  int* cntAll   = (int*)alloc((size_t)NTOT * 4);
  int* Sarr     = (int*)alloc((size_t)(NTOT + 8) * 4);
  int* cursor   = (int*)alloc((size_t)NTOT * 4);
  int* btot     = (int*)alloc((size_t)((NCH + 7) & ~7) * 4);
  int* cvAll    = (int*)alloc((size_t)ETOT * 4);
  unsigned short* wlrb  = (unsigned short*)alloc((size_t)16 * 264 * 2);
  unsigned short* wblr1 = (unsigned short*)alloc((size_t)8 * 512 * 2);
  unsigned short* wblr2 = (unsigned short*)alloc((size_t)8 * 512 * 2);

  // ---- one-shot prologue: CSR + weight prep
  hipMemsetAsync(cntAll, 0, (size_t)NTOT * 4, stream);
  k_prep_count<<<(ETOT + 255) / 256, 256, 0, stream>>>(
      dsts[0], dsts[1], dsts[2], cntAll,
      Wsrc[0], Wdst[0], al[0], ar[0], Wsrc[1], Wdst[1], al[1], ar[1],
      Wsrc[2], Wdst[2], al[2], ar[2], wlrb, wblr1, wblr2, Wb0, Wb1, Wb2);
  k_scanA<<<NCH, 128, 0, stream>>>(cntAll, Sarr, btot, NTOT);
  k_scanB<<<NCH, 256, 0, stream>>>(btot, Sarr, cursor, NTOT, ETOT);
  k_scatter_all<<<(ETOT + 255) / 256, 256, 0, stream>>>(
      srcs[0], dsts[0], srcs[1], dsts[1], srcs[2], dsts[2], cursor, cvAll);

  const unsigned short* Hbf[3] = {nullptr, h1, h2};
  const unsigned short* Wbf[3] = {Wb0, Wb1, Wb2};
  const unsigned short* wblr[3] = {nullptr, wblr1, wblr2};
  const int noff[3] = {0, ND0, ND0 + ND1};

  for (int l = 0; l < 3; ++l) {
    int Ns = L_NS[l], Nd = L_ND[l], Fin = L_FIN[l], Fout = L_FOUT[l];
    if (l == 0) {
      k_dotc_mfma<<<(Ns + 127) / 128, 256, 0, stream>>>(x, wlrb, ell, err, Ns, Nd);
      k_gather4_f32<<<(Nd + 3) / 4, 256, 0, stream>>>(
          x, ell, err, Sarr + noff[l], cvAll, zbf, Nd);
    } else {
      k_dot_gemm<<<(Ns + 127) / 128, 256, 0, stream>>>(
          Hbf[l], wblr[l], ell, err, Ns, Nd);
      k_gather_512<<<Nd, 128, 0, stream>>>(
          Hbf[l], ell, err, Sarr + noff[l], cvAll, zbf);
    }
    dim3 g((Nd + 127) / 128, 1, 4);
    if (l == 0)
      k_gemm_mfma<128, true, true><<<g, 256, 0, stream>>>(zbf, Wbf[l], bb[l], h1, Nd, Fout, Fin);
    else if (l == 1)
      k_gemm_mfma<128, true, true><<<g, 256, 0, stream>>>(zbf, Wbf[l], bb[l], h2, Nd, Fout, Fin);
    else
      k_gemm_mfma<64, false, false><<<g, 256, 0, stream>>>(zbf, Wbf[l], bb[l], rst2, Nd, Fout, Fin);
  }
  k_mean_lsm<<<(1024 + 3) / 4, 256, 0, stream>>>(rst2, (float*)d_out, 1024);
}

// Round 12
// 283.710 us; speedup vs baseline: 1.0424x; 1.0424x over previous
//
#include <hip/hip_runtime.h>
#include <math.h>

// ---------------------------------------------------------------------------
// GAT 3-layer pipeline. bf16 features + MFMA GEMMs, fused CSR edge-softmax.
//   el = h @ wl.T, wl[h,:] = al[h,:] @ Wsrc_h   (no fs materialization)
//   agg = (softmax-weighted sum of raw feats) @ Wsrc_h.T  (aggregate first)
// L0 dot: MFMA-based. L1/L2 dots: shuffle-reduction (proven R9 config).
// ALL gathers: barrier-free, one wave per dst node, 4 nodes/block.
// CSR: concat counts, parallel 2-launch scan, ordinal scatter (R9 config).
// GEMM: global_load_lds(16B) staging, XOR seg-swizzle both sides.
// ---------------------------------------------------------------------------

#define E0 375000
#define E1 90000
#define E2 10240
#define ETOT (E0 + E1 + E2)
#define ND0 25000
#define ND1 6000
#define ND2 1024
#define NTOT (ND0 + ND1 + ND2)   /* 32024 */
#define NCH ((NTOT + 127) / 128) /* 251 */

static const int L_NS[3]   = {150000, 25000, 6000};
static const int L_ND[3]   = {ND0, ND1, ND2};

typedef short bf8_t __attribute__((ext_vector_type(8)));
typedef float f32x4 __attribute__((ext_vector_type(4)));

__device__ __forceinline__ float lrelu(float v) { return v >= 0.f ? v : 0.2f * v; }
__device__ __forceinline__ unsigned short f2b(float f) {
  unsigned u = __float_as_uint(f);
  unsigned r = u + 0x7fffu + ((u >> 16) & 1u);
  return (unsigned short)(r >> 16);
}
__device__ __forceinline__ float b2f(unsigned v) {  // low 16 bits
  return __uint_as_float(v << 16);
}
__device__ __forceinline__ unsigned bpack(float a, float b) {
  return (unsigned)f2b(a) | ((unsigned)f2b(b) << 16);
}

__device__ __forceinline__ void gload16(const unsigned short* g, unsigned short* l) {
  __builtin_amdgcn_global_load_lds(
      (const __attribute__((address_space(1))) unsigned int*)g,
      (__attribute__((address_space(3))) unsigned int*)l, 16, 0, 0);
}

// ---------------- prologue (one-shot, topology/weights only) ----------------

// fused: edge counting (atomics, ordinal out) + wlr tables + bf16 weights
__global__ void k_prep_count(
    const int* __restrict__ d0, const int* __restrict__ d1,
    const int* __restrict__ d2, int* __restrict__ cntAll, int* __restrict__ r,
    const float* __restrict__ Ws0, const float* __restrict__ Wd0,
    const float* __restrict__ al0, const float* __restrict__ ar0,
    const float* __restrict__ Ws1, const float* __restrict__ Wd1,
    const float* __restrict__ al1, const float* __restrict__ ar1,
    const float* __restrict__ Ws2, const float* __restrict__ Wd2,
    const float* __restrict__ al2, const float* __restrict__ ar2,
    unsigned short* __restrict__ wlrb, float* __restrict__ wlr1,
    float* __restrict__ wlr2,
    unsigned short* __restrict__ B0, unsigned short* __restrict__ B1,
    unsigned short* __restrict__ B2) {
  int gid = blockIdx.x * 256 + threadIdx.x;
  if (gid < ETOT) {
    int goff, dv;
    if (gid < E0) { goff = 0; dv = d0[gid]; }
    else if (gid < E0 + E1) { goff = ND0; dv = d1[gid - E0]; }
    else { goff = ND0 + ND1; dv = d2[gid - E0 - E1]; }
    r[gid] = atomicAdd(&cntAll[goff + dv], 1);
  }
  // L0 MFMA-dot B table: bf16 [16][264], rows 8-15 zero
  if (gid < 2048) {
    int h = gid >> 8, k = gid & 255;  // h 0-3: wl, 4-7: wr
    const float* W = (h < 4) ? Ws0 : Wd0;
    const float* a = (h < 4) ? al0 : ar0;
    int hh = h & 3;
    float acc = 0.f;
    for (int d = 0; d < 128; ++d)
      acc += a[hh * 128 + d] * W[(size_t)(hh * 128 + d) * 256 + k];
    wlrb[h * 264 + k] = f2b(acc);
  } else if (gid < 4096) {
    int idx = gid - 2048;
    wlrb[(8 + (idx >> 8)) * 264 + (idx & 255)] = 0;  // zero pad rows
  } else if (gid < 12288) {
    int idx = gid - 4096;  // 0..8191
    float* wlr; const float *Ws, *Wd, *al, *ar; int Fout;
    if (idx < 4096) { wlr = wlr1; Ws = Ws1; Wd = Wd1; al = al1; ar = ar1; Fout = 128; }
    else { idx -= 4096; wlr = wlr2; Ws = Ws2; Wd = Wd2; al = al2; ar = ar2; Fout = 47; }
    int which = idx >> 11;
    int rem = idx & 2047;
    int h = rem >> 9, k = rem & 511;
    const float* W = which ? Wd : Ws;
    const float* a = which ? ar : al;
    float acc = 0.f;
    for (int d = 0; d < Fout; ++d)
      acc += a[h * Fout + d] * W[(size_t)(h * Fout + d) * 512 + k];
    wlr[which * 2048 + rem] = acc;
  }
  // bf16 weight conversion
  const int n0 = 512 * 256, n1 = 512 * 512, n2 = 188 * 512;
  for (int i = gid; i < n0 + n1 + n2; i += gridDim.x * 256) {
    if (i < n0) B0[i] = f2b(Ws0[i]);
    else if (i < n0 + n1) B1[i - n0] = f2b(Ws1[i - n0]);
    else B2[i - n0 - n1] = f2b(Ws2[i - n0 - n1]);
  }
}

// parallel chunked scan, phase A: per-128-chunk local exclusive scan + totals
__global__ __launch_bounds__(128) void k_scanA(const int* __restrict__ cnt,
                                               int* __restrict__ S,
                                               int* __restrict__ btot, int n) {
  __shared__ int wt[2];
  int c = blockIdx.x, t = threadIdx.x, lane = t & 63, w = t >> 6;
  int g = c * 128 + t;
  int v = (g < n) ? cnt[g] : 0;
  int incl = v;
  for (int off = 1; off < 64; off <<= 1) {
    int u = __shfl_up(incl, off);
    if (lane >= off) incl += u;
  }
  if (lane == 63) wt[w] = incl;
  __syncthreads();
  int base = (w == 1) ? wt[0] : 0;
  if (g < n) S[g] = incl - v + base;
  if (t == 127) btot[c] = wt[0] + wt[1];
}

// phase B: add chunk bases (redundant per-block LDS scan of btot)
__global__ __launch_bounds__(256) void k_scanB(const int* __restrict__ btot,
                                               int* __restrict__ S, int n, int etot) {
  __shared__ int tv[256];
  int c = blockIdx.x, t = threadIdx.x;
  int own = (t < NCH) ? btot[t] : 0;
  tv[t] = own;
  __syncthreads();
  for (int off = 1; off < 256; off <<= 1) {
    int u = (t >= off) ? tv[t - off] : 0;
    __syncthreads();
    tv[t] += u;
    __syncthreads();
  }
  int base = tv[c] - btot[c];  // exclusive base of chunk c
  int g = c * 128 + (t & 127);
  if (t < 128 && g < n) S[g] += base;
  if (c == 0 && t == 255) S[n] = etot;
}

__global__ void k_scatter_all(
    const int* __restrict__ s0, const int* __restrict__ d0,
    const int* __restrict__ s1, const int* __restrict__ d1,
    const int* __restrict__ s2, const int* __restrict__ d2,
    const int* __restrict__ S, const int* __restrict__ r,
    int* __restrict__ cvAll) {
  int g = blockIdx.x * 256 + threadIdx.x;
  if (g >= ETOT) return;
  int goff, dv, sv;
  if (g < E0) { goff = 0; dv = d0[g]; sv = s0[g]; }
  else if (g < E0 + E1) { int e = g - E0; goff = ND0; dv = d1[e]; sv = s1[e]; }
  else { int e = g - E0 - E1; goff = ND0 + ND1; dv = d2[e]; sv = s2[e]; }
  cvAll[S[goff + dv] + r[g]] = sv;
}

// ---------------- per-layer feature kernels ----------------

// L0: MFMA dot. Block = 128 nodes, 256 threads (4 waves). fp32 x, cvt in LDS.
__global__ __launch_bounds__(256) void k_dotc_mfma(
    const float* __restrict__ x, const unsigned short* __restrict__ wlrb,
    float* __restrict__ ell, float* __restrict__ err, int Ns, int Nd) {
  __shared__ unsigned short As[128 * 72];
  __shared__ unsigned short Bs[16 * 264];
  const int tid = threadIdx.x;
  const int w = tid >> 6, lane = tid & 63;
  const int bm = blockIdx.x * 128;
  const int rowg = tid >> 4;   // 0..15
  const int seg  = tid & 15;   // 0..15
  for (int i = tid; i < 16 * 264; i += 256) Bs[i] = wlrb[i];
  f32x4 acc[2] = {};
  for (int k0 = 0; k0 < 256; k0 += 64) {
    __syncthreads();
#pragma unroll
    for (int i = 0; i < 8; ++i) {
      int row = rowg + i * 16;
      int gm = bm + row;
      int gmc = gm < Ns ? gm : Ns - 1;
      float4 a = *reinterpret_cast<const float4*>(x + (size_t)gmc * 256 + k0 + seg * 4);
      ushort4 ub;
      ub.x = f2b(a.x); ub.y = f2b(a.y); ub.z = f2b(a.z); ub.w = f2b(a.w);
      *reinterpret_cast<ushort4*>(&As[row * 72 + seg * 4]) = ub;
    }
    __syncthreads();
    const int ra = w * 32 + (lane & 15);
    const int kf = (lane >> 4) * 8;
#pragma unroll
    for (int ks = 0; ks < 2; ++ks) {
      bf8_t b0 = *reinterpret_cast<const bf8_t*>(&Bs[(lane & 15) * 264 + k0 + ks * 32 + kf]);
      bf8_t a0 = *reinterpret_cast<const bf8_t*>(&As[ra * 72 + ks * 32 + kf]);
      bf8_t a1 = *reinterpret_cast<const bf8_t*>(&As[(ra + 16) * 72 + ks * 32 + kf]);
      acc[0] = __builtin_amdgcn_mfma_f32_16x16x32_bf16(a0, b0, acc[0], 0, 0, 0);
      acc[1] = __builtin_amdgcn_mfma_f32_16x16x32_bf16(a1, b0, acc[1], 0, 0, 0);
    }
  }
  int col = lane & 15;
#pragma unroll
  for (int fm = 0; fm < 2; ++fm) {
#pragma unroll
    for (int j = 0; j < 4; ++j) {
      int node = bm + w * 32 + fm * 16 + (lane >> 4) * 4 + j;
      if (node >= Ns) continue;
      float v = acc[fm][j];
      if (col < 4) ell[(size_t)node * 4 + col] = v;
      else if (col < 8 && node < Nd) err[(size_t)node * 4 + (col - 4)] = v;
    }
  }
}

// 8-output cross-lane sum (L1/L2 dots)
__device__ __forceinline__ void reduce8_store(float v[8], int lane, int node, int Nd,
                                              float* __restrict__ ell,
                                              float* __restrict__ err) {
#pragma unroll
  for (int h = 0; h < 8; ++h) {
    v[h] += __shfl_xor(v[h], 8);
    v[h] += __shfl_xor(v[h], 16);
    v[h] += __shfl_xor(v[h], 32);
  }
  int sel = lane >> 3;
  float t01 = (sel & 1) ? v[1] : v[0];
  float t23 = (sel & 1) ? v[3] : v[2];
  float t45 = (sel & 1) ? v[5] : v[4];
  float t67 = (sel & 1) ? v[7] : v[6];
  float t03 = (sel & 2) ? t23 : t01;
  float t47 = (sel & 2) ? t67 : t45;
  float s   = (sel & 4) ? t47 : t03;
  s += __shfl_xor(s, 1);
  s += __shfl_xor(s, 2);
  s += __shfl_xor(s, 4);
  if ((lane & 7) == 0) {
    if (sel < 4) ell[(size_t)node * 4 + sel] = s;
    else if (node < Nd) err[(size_t)node * 4 + (sel - 4)] = s;
  }
}

// layers 1/2: bf16 features, Fin=512, one wave per node.
__global__ __launch_bounds__(256) void k_dot_bf(
    const unsigned short* __restrict__ Hs, const float* __restrict__ wlr,
    float* __restrict__ ell, float* __restrict__ err, int Ns, int Nd) {
  int node = blockIdx.x * 4 + (threadIdx.x >> 6);
  int lane = threadIdx.x & 63;
  if (node >= Ns) return;
  uint4 raw = *reinterpret_cast<const uint4*>(Hs + (size_t)node * 512 + lane * 8);
  float xv[8];
  xv[0] = b2f(raw.x & 0xffffu); xv[1] = b2f(raw.x >> 16);
  xv[2] = b2f(raw.y & 0xffffu); xv[3] = b2f(raw.y >> 16);
  xv[4] = b2f(raw.z & 0xffffu); xv[5] = b2f(raw.z >> 16);
  xv[6] = b2f(raw.w & 0xffffu); xv[7] = b2f(raw.w >> 16);
  bool nR = node < Nd;
  float v[8];
#pragma unroll
  for (int h = 0; h < 4; ++h) {
    const float* wp = wlr + h * 512 + lane * 8;
    float4 w0 = *reinterpret_cast<const float4*>(wp);
    float4 w1 = *reinterpret_cast<const float4*>(wp + 4);
    v[h] = xv[0]*w0.x + xv[1]*w0.y + xv[2]*w0.z + xv[3]*w0.w +
           xv[4]*w1.x + xv[5]*w1.y + xv[6]*w1.z + xv[7]*w1.w;
    v[4 + h] = 0.f;
    if (nR) {
      const float* wq = wlr + 2048 + h * 512 + lane * 8;
      float4 u0 = *reinterpret_cast<const float4*>(wq);
      float4 u1 = *reinterpret_cast<const float4*>(wq + 4);
      v[4 + h] = xv[0]*u0.x + xv[1]*u0.y + xv[2]*u0.z + xv[3]*u0.w +
                 xv[4]*u1.x + xv[5]*u1.y + xv[6]*u1.z + xv[7]*u1.w;
    }
  }
  reduce8_store(v, lane, node, Nd, ell, err);
}

// Unified gather: one WAVE per dst node, 4 nodes per 256-thread block,
// barrier-free (wave-private LDS). F32=true: fp32 X rows (FIN=256, 4 cols/lane).
// F32=false: bf16 rows (FIN=512, 8 cols/lane).
template <int FIN, bool F32>
__global__ __launch_bounds__(256) void k_gather4(
    const void* __restrict__ Hv, const float* __restrict__ ell,
    const float* __restrict__ err, const int* __restrict__ rowptr,
    const int* __restrict__ colv, unsigned short* __restrict__ Z, int Nd) {
  constexpr int CPL = F32 ? 4 : 8;
  constexpr int CAP = 256;
  __shared__ float4 esm_all[4][CAP];
  __shared__ int csm_all[4][CAP];
  int w = threadIdx.x >> 6, lane = threadIdx.x & 63;
  int n = blockIdx.x * 4 + w;
  if (n >= Nd) return;
  float4* esm = esm_all[w];
  int* csm = csm_all[w];
  int beg = rowptr[n], cnt = rowptr[n + 1] - beg;
  float4 er4 = *reinterpret_cast<const float4*>(err + (size_t)n * 4);
  float m0 = -INFINITY, m1 = -INFINITY, m2 = -INFINITY, m3 = -INFINITY;
  for (int i = lane; i < cnt; i += 64) {
    int c = colv[beg + i];
    float4 el4 = *reinterpret_cast<const float4*>(ell + (size_t)c * 4);
    float4 e4;
    e4.x = lrelu(el4.x + er4.x); e4.y = lrelu(el4.y + er4.y);
    e4.z = lrelu(el4.z + er4.z); e4.w = lrelu(el4.w + er4.w);
    if (i < CAP) { csm[i] = c; esm[i] = e4; }
    m0 = fmaxf(m0, e4.x); m1 = fmaxf(m1, e4.y);
    m2 = fmaxf(m2, e4.z); m3 = fmaxf(m3, e4.w);
  }
  for (int off = 32; off > 0; off >>= 1) {
    m0 = fmaxf(m0, __shfl_xor(m0, off));
    m1 = fmaxf(m1, __shfl_xor(m1, off));
    m2 = fmaxf(m2, __shfl_xor(m2, off));
    m3 = fmaxf(m3, __shfl_xor(m3, off));
  }
  __builtin_amdgcn_sched_barrier(0);  // wave-private LDS: order writes before reads
  float s0 = 0.f, s1 = 0.f, s2 = 0.f, s3 = 0.f;
  float acc[4][CPL] = {};

  auto loadrow = [&](int c, float xv[CPL]) {
    if constexpr (F32) {
      float4 a = *reinterpret_cast<const float4*>(
          (const float*)Hv + (size_t)c * FIN + lane * 4);
      xv[0] = a.x; xv[1] = a.y; xv[2] = a.z; xv[3] = a.w;
    } else {
      uint4 raw = *reinterpret_cast<const uint4*>(
          (const unsigned short*)Hv + (size_t)c * FIN + lane * 8);
      xv[0] = b2f(raw.x & 0xffffu); xv[1] = b2f(raw.x >> 16);
      xv[2] = b2f(raw.y & 0xffffu); xv[3] = b2f(raw.y >> 16);
      xv[4] = b2f(raw.z & 0xffffu); xv[5] = b2f(raw.z >> 16);
      xv[6] = b2f(raw.w & 0xffffu); xv[7] = b2f(raw.w >> 16);
    }
  };
  auto accum = [&](float4 w4, const float xv[CPL]) {
    s0 += w4.x; s1 += w4.y; s2 += w4.z; s3 += w4.w;
#pragma unroll
    for (int c2 = 0; c2 < CPL; ++c2) {
      acc[0][c2] = fmaf(w4.x, xv[c2], acc[0][c2]);
      acc[1][c2] = fmaf(w4.y, xv[c2], acc[1][c2]);
      acc[2][c2] = fmaf(w4.z, xv[c2], acc[2][c2]);
      acc[3][c2] = fmaf(w4.w, xv[c2], acc[3][c2]);
    }
  };

  if (cnt <= CAP) {
    for (int i = lane; i < cnt; i += 64) {
      float4 e = esm[i];
      esm[i] = make_float4(__expf(e.x - m0), __expf(e.y - m1),
                           __expf(e.z - m2), __expf(e.w - m3));
    }
    __builtin_amdgcn_sched_barrier(0);
    int j = 0;
    for (; j + 2 <= cnt; j += 2) {
      int c0 = csm[j], c1 = csm[j + 1];
      float4 wa = esm[j], wb = esm[j + 1];
      float xa[CPL], xb[CPL];
      loadrow(c0, xa);
      loadrow(c1, xb);
      accum(wa, xa);
      accum(wb, xb);
    }
    if (j < cnt) {
      float xa[CPL];
      loadrow(csm[j], xa);
      accum(esm[j], xa);
    }
  } else {
    for (int j = 0; j < cnt; ++j) {
      int c = colv[beg + j];
      float4 el4 = *reinterpret_cast<const float4*>(ell + (size_t)c * 4);
      float4 w4;
      w4.x = __expf(lrelu(el4.x + er4.x) - m0);
      w4.y = __expf(lrelu(el4.y + er4.y) - m1);
      w4.z = __expf(lrelu(el4.z + er4.z) - m2);
      w4.w = __expf(lrelu(el4.w + er4.w) - m3);
      float xa[CPL];
      loadrow(c, xa);
      accum(w4, xa);
    }
  }
  float inv[4];
  inv[0] = 1.f / fmaxf(s0, 1e-9f); inv[1] = 1.f / fmaxf(s1, 1e-9f);
  inv[2] = 1.f / fmaxf(s2, 1e-9f); inv[3] = 1.f / fmaxf(s3, 1e-9f);
#pragma unroll
  for (int h = 0; h < 4; ++h) {
    if constexpr (F32) {
      ushort4 o;
      o.x = f2b(acc[h][0] * inv[h]); o.y = f2b(acc[h][1] * inv[h]);
      o.z = f2b(acc[h][2] * inv[h]); o.w = f2b(acc[h][3] * inv[h]);
      *reinterpret_cast<ushort4*>(Z + (size_t)n * 4 * FIN + h * FIN + lane * 4) = o;
    } else {
      uint4 o;
      o.x = bpack(acc[h][0] * inv[h], acc[h][1] * inv[h]);
      o.y = bpack(acc[h][2] * inv[h], acc[h][3] * inv[h]);
      o.z = bpack(acc[h][4] * inv[h], acc[h][5] * inv[h]);
      o.w = bpack(acc[h][6] * inv[h], acc[h][7] * inv[h]);
      *reinterpret_cast<uint4*>(Z + (size_t)n * 4 * FIN + h * FIN + lane * 8) = o;
    }
  }
}

// bf16 MFMA GEMM (unchanged, proven)
template <int BN, bool ACT, bool OUTBF>
__global__ __launch_bounds__(256) void k_gemm_mfma(
    const unsigned short* __restrict__ Zb, const unsigned short* __restrict__ Wb,
    const float* __restrict__ bias, void* __restrict__ outv,
    int M, int N, int K) {
  constexpr int FN = BN / 16;
  constexpr int AI = 4;
  constexpr int BI = BN / 32;
  int h = blockIdx.z;
  __shared__ unsigned short As[128 * 64];
  __shared__ unsigned short Bs[BN * 64];
  const int tid = threadIdx.x;
  const int w = tid >> 6, lane = tid & 63;
  const int bm = blockIdx.x * 128, bn = blockIdx.y * BN;
  const int lda = 4 * K;
  const unsigned short* Ag = Zb + (size_t)h * K;
  const unsigned short* Bg = Wb + (size_t)h * N * K;
  const int lrow = lane >> 3;
  const int gseg = (lane & 7) ^ lrow;
  f32x4 acc[2][FN];
#pragma unroll
  for (int i = 0; i < 2; ++i)
#pragma unroll
    for (int j = 0; j < FN; ++j) acc[i][j] = (f32x4){0.f, 0.f, 0.f, 0.f};

  for (int k0 = 0; k0 < K; k0 += 64) {
    __syncthreads();
#pragma unroll
    for (int i = 0; i < AI; ++i) {
      int ch = w * AI + i;
      int row = ch * 8 + lrow;
      int gm = bm + row; gm = gm < M ? gm : M - 1;
      gload16(Ag + (size_t)gm * lda + k0 + gseg * 8, As + ch * 512);
    }
#pragma unroll
    for (int i = 0; i < BI; ++i) {
      int ch = w * BI + i;
      int row = ch * 8 + lrow;
      int gn = bn + row; gn = gn < N ? gn : N - 1;
      gload16(Bg + (size_t)gn * K + k0 + gseg * 8, Bs + ch * 512);
    }
    __syncthreads();
    const int ra = w * 32 + (lane & 15);
#pragma unroll
    for (int ks = 0; ks < 2; ++ks) {
      int cs = ((((ks << 2) + (lane >> 4)) ^ (lane & 7)) << 3);
      bf8_t a0 = *reinterpret_cast<const bf8_t*>(As + ra * 64 + cs);
      bf8_t a1 = *reinterpret_cast<const bf8_t*>(As + (ra + 16) * 64 + cs);
#pragma unroll
      for (int fn = 0; fn < FN; ++fn) {
        bf8_t bf = *reinterpret_cast<const bf8_t*>(Bs + (fn * 16 + (lane & 15)) * 64 + cs);
        acc[0][fn] = __builtin_amdgcn_mfma_f32_16x16x32_bf16(a0, bf, acc[0][fn], 0, 0, 0);
        acc[1][fn] = __builtin_amdgcn_mfma_f32_16x16x32_bf16(a1, bf, acc[1][fn], 0, 0, 0);
      }
    }
  }
  int ldo = 4 * N;
#pragma unroll
  for (int fm = 0; fm < 2; ++fm) {
#pragma unroll
    for (int fn = 0; fn < FN; ++fn) {
      int colb = bn + fn * 16 + (lane & 15);
      if (colb >= N) continue;
      float bv = bias[h * N + colb];
#pragma unroll
      for (int j = 0; j < 4; ++j) {
        int rowb = bm + w * 32 + fm * 16 + (lane >> 4) * 4 + j;
        if (rowb >= M) continue;
        float v = acc[fm][fn][j] + bv;
        if (ACT) v = v > 0.f ? v : (__expf(v) - 1.f);
        size_t off = (size_t)rowb * ldo + (size_t)h * N + colb;
        if (OUTBF) ((unsigned short*)outv)[off] = f2b(v);
        else ((float*)outv)[off] = v;
      }
    }
  }
}

// mean over 4 heads (C=47) + log_softmax; one wave per node
__global__ __launch_bounds__(256) void k_mean_lsm(const float* __restrict__ rst2,
                                                  float* __restrict__ out, int Nd) {
  int node = blockIdx.x * 4 + (threadIdx.x >> 6);
  int lane = threadIdx.x & 63;
  if (node >= Nd) return;
  const float* r = rst2 + (size_t)node * 188;
  float vv = 0.f;
  if (lane < 47)
    vv = 0.25f * (r[lane] + r[47 + lane] + r[94 + lane] + r[141 + lane]);
  float m = (lane < 47) ? vv : -INFINITY;
  for (int off = 32; off > 0; off >>= 1) m = fmaxf(m, __shfl_xor(m, off));
  float ex = (lane < 47) ? __expf(vv - m) : 0.f;
  float ss = ex;
  for (int off = 32; off > 0; off >>= 1) ss += __shfl_xor(ss, off);
  if (lane < 47) out[(size_t)node * 47 + lane] = vv - m - logf(ss);
}

extern "C" void kernel_launch(void* const* d_in, const int* in_sizes, int n_in,
                              void* d_out, int out_size, void* d_ws, size_t ws_size,
                              hipStream_t stream) {
  (void)in_sizes; (void)n_in; (void)out_size; (void)ws_size;
  const float* x = (const float*)d_in[0];
  const int* srcs[3] = {(const int*)d_in[1], (const int*)d_in[3], (const int*)d_in[5]};
  const int* dsts[3] = {(const int*)d_in[2], (const int*)d_in[4], (const int*)d_in[6]};
  const float* Wsrc[3] = {(const float*)d_in[7], (const float*)d_in[12], (const float*)d_in[17]};
  const float* Wdst[3] = {(const float*)d_in[8], (const float*)d_in[13], (const float*)d_in[18]};
  const float* al[3]   = {(const float*)d_in[9], (const float*)d_in[14], (const float*)d_in[19]};
  const float* ar[3]   = {(const float*)d_in[10], (const float*)d_in[15], (const float*)d_in[20]};
  const float* bb[3]   = {(const float*)d_in[11], (const float*)d_in[16], (const float*)d_in[21]};

  char* p = (char*)d_ws;
  auto alloc = [&](size_t bytes) -> void* {
    void* r = (void*)p;
    p += (bytes + 255) & ~(size_t)255;
    return r;
  };
  unsigned short* zbf = (unsigned short*)alloc((size_t)25000 * 1024 * 2);
  unsigned short* h1  = (unsigned short*)alloc((size_t)25000 * 512 * 2);
  unsigned short* h2  = (unsigned short*)alloc((size_t)6000 * 512 * 2);
  float* rst2   = (float*)alloc((size_t)1024 * 188 * 4);
  unsigned short* Wb0 = (unsigned short*)alloc((size_t)512 * 256 * 2);
  unsigned short* Wb1 = (unsigned short*)alloc((size_t)512 * 512 * 2);
  unsigned short* Wb2 = (unsigned short*)alloc((size_t)188 * 512 * 2);
  float* ell    = (float*)alloc((size_t)150000 * 4 * 4);
  float* err    = (float*)alloc((size_t)25000 * 4 * 4);
  int* cntAll   = (int*)alloc((size_t)NTOT * 4);
  int* Sarr     = (int*)alloc((size_t)(NTOT + 8) * 4);
  int* btot     = (int*)alloc((size_t)((NCH + 7) & ~7) * 4);
  int* r_all    = (int*)alloc((size_t)ETOT * 4);
  int* cvAll    = (int*)alloc((size_t)ETOT * 4);
  unsigned short* wlrb = (unsigned short*)alloc((size_t)16 * 264 * 2);
  float* wlr1   = (float*)alloc((size_t)8 * 512 * 4);
  float* wlr2   = (float*)alloc((size_t)8 * 512 * 4);

  // ---- one-shot prologue: CSR + weight prep
  hipMemsetAsync(cntAll, 0, (size_t)NTOT * 4, stream);
  k_prep_count<<<(ETOT + 255) / 256, 256, 0, stream>>>(
      dsts[0], dsts[1], dsts[2], cntAll, r_all,
      Wsrc[0], Wdst[0], al[0], ar[0], Wsrc[1], Wdst[1], al[1], ar[1],
      Wsrc[2], Wdst[2], al[2], ar[2], wlrb, wlr1, wlr2, Wb0, Wb1, Wb2);
  k_scanA<<<NCH, 128, 0, stream>>>(cntAll, Sarr, btot, NTOT);
  k_scanB<<<NCH, 256, 0, stream>>>(btot, Sarr, NTOT, ETOT);
  k_scatter_all<<<(ETOT + 255) / 256, 256, 0, stream>>>(
      srcs[0], dsts[0], srcs[1], dsts[1], srcs[2], dsts[2], Sarr, r_all, cvAll);

  const unsigned short* Hbf[3] = {nullptr, h1, h2};
  const unsigned short* Wbf[3] = {Wb0, Wb1, Wb2};
  const float* wlrs[3] = {nullptr, wlr1, wlr2};
  const int noff[3] = {0, ND0, ND0 + ND1};

  for (int l = 0; l < 3; ++l) {
    int Ns = L_NS[l], Nd = L_ND[l];
    if (l == 0) {
      k_dotc_mfma<<<(Ns + 127) / 128, 256, 0, stream>>>(x, wlrb, ell, err, Ns, Nd);
      k_gather4<256, true><<<(Nd + 3) / 4, 256, 0, stream>>>(
          x, ell, err, Sarr + noff[l], cvAll, zbf, Nd);
    } else {
      k_dot_bf<<<(Ns + 3) / 4, 256, 0, stream>>>(Hbf[l], wlrs[l], ell, err, Ns, Nd);
      k_gather4<512, false><<<(Nd + 3) / 4, 256, 0, stream>>>(
          Hbf[l], ell, err, Sarr + noff[l], cvAll, zbf, Nd);
    }
    dim3 g((Nd + 127) / 128, 1, 4);
    if (l == 0)
      k_gemm_mfma<128, true, true><<<g, 256, 0, stream>>>(zbf, Wbf[l], bb[l], h1, Nd, 128, 256);
    else if (l == 1)
      k_gemm_mfma<128, true, true><<<g, 256, 0, stream>>>(zbf, Wbf[l], bb[l], h2, Nd, 128, 512);
    else
      k_gemm_mfma<64, false, false><<<g, 256, 0, stream>>>(zbf, Wbf[l], bb[l], rst2, Nd, 47, 512);
  }
  k_mean_lsm<<<(1024 + 3) / 4, 256, 0, stream>>>(rst2, (float*)d_out, 1024);
}